// Round 1
// baseline (670.288 us; speedup 1.0000x reference)
//
#include <hip/hip_runtime.h>

#define D_DIM 128
#define TILE_ROWS 64
#define THREADS 256
// log2(10000)/64
#define THETA_L2 (13.287712379549449f / 64.0f)
// log2(2*pi)
#define LOG2_2PI 2.6514961294723187f

typedef __attribute__((ext_vector_type(8))) __bf16 bf16x8;
typedef __attribute__((ext_vector_type(4))) float f32x4;

union U8 { bf16x8 v; unsigned short u[8]; };

__device__ inline unsigned short f2bf(float f) {
    unsigned int u = __builtin_bit_cast(unsigned int, f);
    u = (u + 0x7fffu + ((u >> 16) & 1u)) >> 16;
    return (unsigned short)u;
}

// batch is sorted; first element of each run writes its index (unique writer, no atomics).
__global__ void seg_first_kernel(const int* __restrict__ batch, int* __restrict__ seg_first, int N) {
    int i = blockIdx.x * blockDim.x + threadIdx.x;
    if (i < N) {
        int b = batch[i];
        if (i == 0 || batch[i - 1] != b) seg_first[b] = i;
    }
}

__global__ __launch_bounds__(THREADS, 3)
void readout_kernel(const float* __restrict__ x, const int* __restrict__ batch,
                    const int* __restrict__ seg_first,
                    const float* __restrict__ W1, const float* __restrict__ b1,
                    const float* __restrict__ W2, const float* __restrict__ b2,
                    float* __restrict__ out, int N, int ntiles) {
    const int tid  = threadIdx.x;
    const int wave = tid >> 6;
    const int lane = tid & 63;
    const int lr   = lane & 15;   // MFMA "n"/"m" lane row
    const int quad = lane >> 4;

    __shared__ __align__(16) unsigned short xs[TILE_ROWS * 136]; // bf16 x tile, padded stride
    __shared__ float posS[TILE_ROWS];
    __shared__ float redS[4][TILE_ROWS];

    // Each wave owns d-slice [wave*32, wave*32+32). A-fragments (W1, bf16) live in
    // registers for the whole kernel: 2 dtiles x 4 ksteps x 4 VGPR = 32 VGPRs.
    bf16x8 afrag[2][4];
    float b1r[2][4], w2r[2][4], thr[2][2]; // per-lane epilogue constants (d fixed per lane)
    #pragma unroll
    for (int dt = 0; dt < 2; ++dt) {
        int drow = wave * 32 + dt * 16 + lr;  // A-operand row m = lane&15
        #pragma unroll
        for (int ks = 0; ks < 4; ++ks) {
            const float* src = W1 + drow * D_DIM + ks * 32 + quad * 8; // k = quad*8 + j
            float4 f0 = *(const float4*)(src);
            float4 f1 = *(const float4*)(src + 4);
            U8 t;
            t.u[0] = f2bf(f0.x); t.u[1] = f2bf(f0.y); t.u[2] = f2bf(f0.z); t.u[3] = f2bf(f0.w);
            t.u[4] = f2bf(f1.x); t.u[5] = f2bf(f1.y); t.u[6] = f2bf(f1.z); t.u[7] = f2bf(f1.w);
            afrag[dt][ks] = t.v;
        }
        int dbase = wave * 32 + dt * 16 + quad * 4;  // C/D layout: row = quad*4 + reg
        #pragma unroll
        for (int j = 0; j < 4; ++j) { b1r[dt][j] = b1[dbase + j]; w2r[dt][j] = W2[dbase + j]; }
        int p0 = dbase >> 1;  // pair indices p0, p0+1 both inside this lane
        // theta_p / (2*pi): angle in revolutions for HW v_sin/v_cos
        thr[dt][0] = exp2f(-(float)p0 * THETA_L2 - LOG2_2PI);
        thr[dt][1] = exp2f(-(float)(p0 + 1) * THETA_L2 - LOG2_2PI);
    }
    const int lastid = batch[N - 1];
    const float b2v = b2[0];

    for (int t = blockIdx.x; t < ntiles; t += gridDim.x) {
        const int row0 = t * TILE_ROWS;
        __syncthreads();  // previous iter's xs/redS reads done before restaging

        // Stage x tile: fp32 -> bf16 into LDS. Fully coalesced: lane-contiguous 16B.
        #pragma unroll
        for (int i = 0; i < 8; ++i) {
            int e = i * 1024 + tid * 4;          // element offset within 64x128 tile
            int r = e >> 7, c = e & 127;
            int grow = row0 + r;
            float4 f = {0.f, 0.f, 0.f, 0.f};
            if (grow < N) f = *(const float4*)(x + grow * D_DIM + c);
            ushort4 pk;
            pk.x = f2bf(f.x); pk.y = f2bf(f.y); pk.z = f2bf(f.z); pk.w = f2bf(f.w);
            *(ushort4*)(&xs[r * 136 + c]) = pk;
        }
        if (tid < TILE_ROWS) {
            int grow = row0 + tid;
            float p = 0.f;
            if (grow < N) {
                int b = batch[grow];
                if (b != lastid) p = (float)(grow - seg_first[b]);  // pos=0 => rope = identity
            }
            posS[tid] = p;
        }
        __syncthreads();

        #pragma unroll
        for (int nt = 0; nt < 4; ++nt) {
            const int rloc = nt * 16 + lr;       // x row within tile for this lane
            bf16x8 bfr[4];
            #pragma unroll
            for (int ks = 0; ks < 4; ++ks)       // B[k=quad*8+j][n=lane&15]
                bfr[ks] = *(const bf16x8*)(&xs[rloc * 136 + ks * 32 + quad * 8]);
            f32x4 acc0 = {0.f, 0.f, 0.f, 0.f};
            f32x4 acc1 = {0.f, 0.f, 0.f, 0.f};
            #pragma unroll
            for (int ks = 0; ks < 4; ++ks) {
                acc0 = __builtin_amdgcn_mfma_f32_16x16x32_bf16(afrag[0][ks], bfr[ks], acc0, 0, 0, 0);
                acc1 = __builtin_amdgcn_mfma_f32_16x16x32_bf16(afrag[1][ks], bfr[ks], acc1, 0, 0, 0);
            }
            const float posv = posS[rloc];
            float part = 0.f;
            #pragma unroll
            for (int dt = 0; dt < 2; ++dt) {
                f32x4 a = dt ? acc1 : acc0;
                float h0 = a[0] + b1r[dt][0];
                float h1 = a[1] + b1r[dt][1];
                float h2 = a[2] + b1r[dt][2];
                float h3 = a[3] + b1r[dt][3];
                // angle in revolutions; explicit fract reduction then HW sin/cos
                float rev0 = posv * thr[dt][0];
                float rev1 = posv * thr[dt][1];
                float fr0 = rev0 - floorf(rev0);
                float fr1 = rev1 - floorf(rev1);
                float s0 = __builtin_amdgcn_sinf(fr0), c0 = __builtin_amdgcn_cosf(fr0);
                float s1 = __builtin_amdgcn_sinf(fr1), c1 = __builtin_amdgcn_cosf(fr1);
                float r0 = h0 * c0 - h1 * s0;
                float r1 = h1 * c0 + h0 * s0;
                float r2 = h2 * c1 - h3 * s1;
                float r3 = h3 * c1 + h2 * s1;
                part += r0 * w2r[dt][0] + r1 * w2r[dt][1] + r2 * w2r[dt][2] + r3 * w2r[dt][3];
            }
            // reduce over the 4 quads (they hold disjoint d within this wave's slice)
            part += __shfl_xor(part, 16, 64);
            part += __shfl_xor(part, 32, 64);
            if (quad == 0) redS[wave][rloc] = part;
        }
        __syncthreads();
        if (tid < TILE_ROWS) {
            int grow = row0 + tid;
            if (grow < N)
                out[grow] = redS[0][tid] + redS[1][tid] + redS[2][tid] + redS[3][tid] + b2v;
        }
    }
}

extern "C" void kernel_launch(void* const* d_in, const int* in_sizes, int n_in,
                              void* d_out, int out_size, void* d_ws, size_t ws_size,
                              hipStream_t stream) {
    const float* x     = (const float*)d_in[0];
    const int*   batch = (const int*)d_in[1];
    const float* W1    = (const float*)d_in[2];
    const float* b1    = (const float*)d_in[3];
    const float* W2    = (const float*)d_in[4];
    const float* b2    = (const float*)d_in[5];
    float* out = (float*)d_out;
    const int N = in_sizes[1];

    int* seg_first = (int*)d_ws;  // 4096 ints; only ids present in batch are written/read

    seg_first_kernel<<<(N + 255) / 256, 256, 0, stream>>>(batch, seg_first, N);

    const int ntiles = (N + TILE_ROWS - 1) / TILE_ROWS;
    const int grid = ntiles < 1024 ? ntiles : 1024;
    readout_kernel<<<grid, THREADS, 0, stream>>>(x, batch, seg_first, W1, b1, W2, b2, out, N, ntiles);
}